// Round 3
// baseline (346.560 us; speedup 1.0000x reference)
//
#include <hip/hip_runtime.h>

#define BATCH 16384
#define DIM 128
#define NLINK 500
#define NG 16           // 16 groups x 32 lanes = 512 threads
#define CAP 128         // per-link bucket capacity (Poisson mean 32.8)

// async global->LDS, 16B per lane; LDS dst is wave-uniform base + lane*16 (linear in t).
__device__ __forceinline__ void gload_lds16(const float* g, float* l) {
    __builtin_amdgcn_global_load_lds(
        (const __attribute__((address_space(1))) void*)g,
        (__attribute__((address_space(3))) void*)l, 16, 0, 0);
}

__global__ void k_init(float* __restrict__ out) {
    if (threadIdx.x == 0) out[0] = 0.0f;
}

#define FMA4(acc, m, s)                                          \
    acc.x = fmaf(m.x, s, acc.x); acc.y = fmaf(m.y, s, acc.y);    \
    acc.z = fmaf(m.z, s, acc.z); acc.w = fmaf(m.w, s, acc.w);

// one M-column-quad per lane feeds 8 accumulators (pos/neg x 4 samples):
#define STEP(M_, C_)                                             \
    FMA4(a0, M_, v0.C_) FMA4(a1, M_, v1.C_)                      \
    FMA4(a2, M_, v2.C_) FMA4(a3, M_, v3.C_)                      \
    FMA4(a4, M_, v4.C_) FMA4(a5, M_, v5.C_)                      \
    FMA4(a6, M_, v6.C_) FMA4(a7, M_, v7.C_)

// One block per link. 512 threads = 16 groups (g=t>>5) x 32 lanes (q=t&31).
// QUAD scheme: group g handles samples slist[4g..4g+3] in ONE sweep — each
// M ds_read_b128 feeds 8 accumulators (4 samples x pos/neg), cutting LDS-pipe
// demand ~38% vs the pair scheme. With count<=64 each group runs at most one
// unit (loop kept only as a safety net). Barrier-free after the stage drain:
// each group's dv rows are touched only by its own 32 lanes (intra-wave
// lgkmcnt ordering), so waves drift and exit early.
__global__ __launch_bounds__(512, 2) void k_fused(
    const float* __restrict__ node_w, const float* __restrict__ link_w,
    const float* __restrict__ transfer_w,
    const int* __restrict__ sp, const int* __restrict__ tp,
    const int* __restrict__ sn, const int* __restrict__ tn,
    const int* __restrict__ r, float* __restrict__ out)
{
    __shared__ float Ms[DIM * DIM];          // 64 KB, full M row-major [d][e]
    __shared__ float dv[NG * 8 * DIM];       // 64 KB: per group 8 diff vectors
                                             //   (p0,n0,p1,n1,p2,n2,p3,n3)
    __shared__ int   slist[CAP];
    __shared__ int   cnt;
    __shared__ float lossbuf[NG];
    // ~130 KB total -> 1 block/CU, 8 waves (unchanged occupancy)

    const int link = blockIdx.x;
    const int t = threadIdx.x;
    const int g = t >> 5;
    const int q = t & 31;

    if (t == 0) cnt = 0;
    __syncthreads();

    // r loads (held in regs through the scan)
    int4 rv[8];
    #pragma unroll
    for (int j = 0; j < 8; j++) rv[j] = ((const int4*)r)[j * 512 + t];

    // async-stage full 64 KB M into LDS (8 x 16B per thread, linear both sides).
    {
        const float* src = transfer_w + (size_t)link * (DIM * DIM);
        #pragma unroll
        for (int i = 0; i < 8; i++) {
            const int c = (t + 512 * i) * 4;
            gload_lds16(src + c, Ms + c);
        }
    }

    // compact this link's sample indices (runs while M loads are in flight)
    #pragma unroll
    for (int j = 0; j < 8; j++) {
        const int bi = (j * 512 + t) * 4;
        if (rv[j].x == link) slist[atomicAdd(&cnt, 1)] = bi;
        if (rv[j].y == link) slist[atomicAdd(&cnt, 1)] = bi + 1;
        if (rv[j].z == link) slist[atomicAdd(&cnt, 1)] = bi + 2;
        if (rv[j].w == link) slist[atomicAdd(&cnt, 1)] = bi + 3;
    }
    __syncthreads();   // drains vmcnt(0): Ms complete; slist/cnt visible

    const int count = cnt;
    float* gbase = dv + (g * 8) * DIM;       // this group's 8 diff rows
    const float4* M4 = (const float4*)Ms;
    float lsum = 0.0f;

    for (int u0 = 4 * g; u0 < count; u0 += 4 * NG) {   // normally <=1 iteration
        // link embedding per thread (L2 hit), needed in epilogue
        const float4 re = ((const float4*)(link_w + (size_t)link * DIM))[q];

        // sample indices with pad-duplication (padded results are discarded)
        const int b0 = slist[u0];
        const int b1 = slist[(u0 + 1 < count) ? u0 + 1 : count - 1];
        const int b2 = slist[(u0 + 2 < count) ? u0 + 2 : count - 1];
        const int b3 = slist[(u0 + 3 < count) ? u0 + 3 : count - 1];

        // gather 16 node rows (issued together for ILP)
        #define ROW(idx) (((const float4*)(node_w + (size_t)(idx) * DIM))[q])
        float4 A0 = ROW(sp[b0]), C0 = ROW(tp[b0]), E0 = ROW(sn[b0]), F0 = ROW(tn[b0]);
        float4 A1 = ROW(sp[b1]), C1 = ROW(tp[b1]), E1 = ROW(sn[b1]), F1 = ROW(tn[b1]);
        float4 A2 = ROW(sp[b2]), C2 = ROW(tp[b2]), E2 = ROW(sn[b2]), F2 = ROW(tn[b2]);
        float4 A3 = ROW(sp[b3]), C3 = ROW(tp[b3]), E3 = ROW(sn[b3]), F3 = ROW(tn[b3]);
        #undef ROW

        // 8 diff vectors -> LDS (each 512 B contiguous per group, conflict-free)
        {
            float4 w_;
            #define DIFF(vec, X, Y)                                              \
                w_.x = X.x - Y.x; w_.y = X.y - Y.y;                              \
                w_.z = X.z - Y.z; w_.w = X.w - Y.w;                              \
                ((float4*)(gbase + (vec) * DIM))[q] = w_;
            DIFF(0, A0, C0) DIFF(1, E0, F0)
            DIFF(2, A1, C1) DIFF(3, E1, F1)
            DIFF(4, A2, C2) DIFF(5, E2, F2)
            DIFF(6, A3, C3) DIFF(7, E3, F3)
            #undef DIFF
        }

        float4 a0 = {0,0,0,0}, a1 = {0,0,0,0}, a2 = {0,0,0,0}, a3 = {0,0,0,0};
        float4 a4 = {0,0,0,0}, a5 = {0,0,0,0}, a6 = {0,0,0,0}, a7 = {0,0,0,0};
        const float4* V0 = (const float4*)(gbase + 0 * DIM);
        const float4* V1 = (const float4*)(gbase + 1 * DIM);
        const float4* V2 = (const float4*)(gbase + 2 * DIM);
        const float4* V3 = (const float4*)(gbase + 3 * DIM);
        const float4* V4 = (const float4*)(gbase + 4 * DIM);
        const float4* V5 = (const float4*)(gbase + 5 * DIM);
        const float4* V6 = (const float4*)(gbase + 6 * DIM);
        const float4* V7 = (const float4*)(gbase + 7 * DIM);

        #pragma unroll 2
        for (int d4 = 0; d4 < 32; d4++) {
            float4 v0 = V0[d4], v1 = V1[d4], v2 = V2[d4], v3 = V3[d4];  // broadcasts
            float4 v4 = V4[d4], v5 = V5[d4], v6 = V6[d4], v7 = V7[d4];
            float4 m0 = M4[(4 * d4 + 0) * 32 + q];   // one M sweep, 8 matvecs
            float4 m1 = M4[(4 * d4 + 1) * 32 + q];
            float4 m2 = M4[(4 * d4 + 2) * 32 + q];
            float4 m3 = M4[(4 * d4 + 3) * 32 + q];
            STEP(m0, x) STEP(m1, y) STEP(m2, z) STEP(m3, w)
        }

        // per-sample loss partials (identical per-sample FP order to prior kernel)
        #define LOSS(ACp, ACn)                                                   \
            (fabsf(ACp.x + re.x) + fabsf(ACp.y + re.y) +                         \
             fabsf(ACp.z + re.z) + fabsf(ACp.w + re.w)                           \
           - fabsf(ACn.x + re.x) - fabsf(ACn.y + re.y)                           \
           - fabsf(ACn.z + re.z) - fabsf(ACn.w + re.w))
        float s0 = LOSS(a0, a1);
        float s1 = LOSS(a2, a3);
        float s2 = LOSS(a4, a5);
        float s3 = LOSS(a6, a7);
        #undef LOSS
        #pragma unroll
        for (int o = 16; o >= 1; o >>= 1) {
            s0 += __shfl_xor(s0, o, 32);
            s1 += __shfl_xor(s1, o, 32);
            s2 += __shfl_xor(s2, o, 32);
            s3 += __shfl_xor(s3, o, 32);
        }
        if (q == 0) {
            lsum += fmaxf(s0 + 1.0f, 0.0f);
            if (u0 + 1 < count) lsum += fmaxf(s1 + 1.0f, 0.0f);
            if (u0 + 2 < count) lsum += fmaxf(s2 + 1.0f, 0.0f);
            if (u0 + 3 < count) lsum += fmaxf(s3 + 1.0f, 0.0f);
        }
    }

    if (q == 0) lossbuf[g] = lsum;       // every group writes (0 if idle)
    __syncthreads();
    if (t == 0) {
        float s = 0.0f;
        #pragma unroll
        for (int i = 0; i < NG; i++) s += lossbuf[i];
        atomicAdd(out, s * (1.0f / BATCH));
    }
}

extern "C" void kernel_launch(void* const* d_in, const int* in_sizes, int n_in,
                              void* d_out, int out_size, void* d_ws, size_t ws_size,
                              hipStream_t stream) {
    const float* node_w     = (const float*)d_in[0];
    const float* link_w     = (const float*)d_in[1];
    const float* transfer_w = (const float*)d_in[2];
    const int* sp = (const int*)d_in[3];
    const int* tp = (const int*)d_in[4];
    const int* sn = (const int*)d_in[5];
    const int* tn = (const int*)d_in[6];
    const int* r  = (const int*)d_in[7];
    float* out = (float*)d_out;
    (void)d_ws; (void)ws_size;

    k_init<<<1, 64, 0, stream>>>(out);
    k_fused<<<NLINK, 512, 0, stream>>>(node_w, link_w, transfer_w,
                                       sp, tp, sn, tn, r, out);
}